// Round 14
// baseline (317.992 us; speedup 1.0000x reference)
//
#include <hip/hip_runtime.h>
#include <hip/hip_bf16.h>
#include <cstdint>
#include <cstddef>

#define NTOK 8192
#define DH   2048
#define DF   1376
#define NE   8
#define CAP  1280

typedef __bf16 bf16x8 __attribute__((ext_vector_type(8)));
typedef float  f32x4  __attribute__((ext_vector_type(4)));

#define BARRIER() asm volatile("s_barrier" ::: "memory")
#define WAITV(n)  asm volatile("s_waitcnt vmcnt(" #n ")" ::: "memory")
#define LGKM(n)   asm volatile("s_waitcnt lgkmcnt(" #n ")" ::: "memory")
#define SCHED0()  __builtin_amdgcn_sched_barrier(0)
#define SETPRIO(n) __builtin_amdgcn_s_setprio(n)

__device__ __forceinline__ uint32_t pk2(float a, float b) {
  float2 f; f.x = a; f.y = b;
  union { __hip_bfloat162 h; uint32_t u; } cv;
  cv.h = __float22bfloat162_rn(f);
  return cv.u;
}
__device__ __forceinline__ ushort bf16bits(float a) {
  return (ushort)(pk2(a, 0.f) & 0xFFFFu);
}
__device__ __forceinline__ void gload16(const ushort* g, ushort* l) {
  __builtin_amdgcn_global_load_lds(
      (const __attribute__((address_space(1))) uint32_t*)(const void*)g,
      (__attribute__((address_space(3))) uint32_t*)(void*)l,
      16, 0, 0);
}

// rowpair-128B swizzle (proven 0-conflict), baked into global operand
// buffers by prep; all global_load_lds are lane-contiguous.
__device__ __forceinline__ int rp_off(int row, int l4) {
  return ((row >> 1) << 7) + (((((row & 1) << 2) + l4) ^ ((row >> 1) & 7)) << 4);
}

// ---------------- routing: slot<-token and token->slot maps ----------------
__global__ void routing_kernel(const int* __restrict__ idx, int* __restrict__ tok_slot,
                               int* __restrict__ tok2slot) {
  __shared__ int cnt[256][NE];
  const int t = threadIdx.x;
  for (int s = t; s < NE * CAP; s += 256) tok_slot[s] = -1;
  unsigned long long cA = 0ull, cB = 0ull;
  const int per = NTOK / 256, base = t * per;
  for (int i = 0; i < per; ++i) {
    int e = idx[base + i];
    unsigned long long inc = 1ull << ((e & 3) * 16);
    if (e < 4) cA += inc; else cB += inc;
  }
#pragma unroll
  for (int e = 0; e < 4; ++e) cnt[t][e]     = (int)((cA >> (e * 16)) & 0xFFFF);
#pragma unroll
  for (int e = 0; e < 4; ++e) cnt[t][4 + e] = (int)((cB >> (e * 16)) & 0xFFFF);
  __syncthreads();
  if (t < NE) {
    int run = 0;
    for (int i = 0; i < 256; ++i) { int c = cnt[i][t]; cnt[i][t] = run; run += c; }
  }
  __syncthreads();
  cA = 0ull; cB = 0ull;
#pragma unroll
  for (int e = 0; e < 4; ++e) cA |= (unsigned long long)(cnt[t][e] & 0xFFFF) << (e * 16);
#pragma unroll
  for (int e = 0; e < 4; ++e) cB |= (unsigned long long)(cnt[t][4 + e] & 0xFFFF) << (e * 16);
  for (int i = 0; i < per; ++i) {
    int token = base + i;
    int e = idx[token];
    int sh = (e & 3) * 16;
    int r = (int)(((e < 4 ? cA : cB) >> sh) & 0xFFFF);
    unsigned long long inc = 1ull << sh;
    if (e < 4) cA += inc; else cB += inc;
    bool keep = (r < CAP);
    tok2slot[token] = keep ? (e * CAP + r) : -1;
    if (keep) tok_slot[e * CAP + r] = token;
  }
}

// ---------------- prep1: z<8 wg, z<16 wu -> tiled-swizzled; z>=16 x -> gathered tiled xb2 + y-zero ----------------
__global__ __launch_bounds__(256) void prep1(
    const float* __restrict__ wg, const float* __restrict__ wu,
    ushort* __restrict__ wgt, ushort* __restrict__ wut,
    const float* __restrict__ x, const int* __restrict__ tok2slot,
    ushort* __restrict__ xb2, float* __restrict__ y) {
  const int z = blockIdx.z;
  const int tid = threadIdx.x;
  if (z >= 16) {
    const int row = (z - 16) * 1024 + blockIdx.y * 32 + blockIdx.x;
    const int k0 = tid * 8;
    const size_t off = (size_t)row * DH + k0;
    float4 a = *(const float4*)(x + off);
    float4 b = *(const float4*)(x + off + 4);
    uint4 p4 = { pk2(a.x, a.y), pk2(a.z, a.w), pk2(b.x, b.y), pk2(b.z, b.w) };
    int slotg = tok2slot[row];
    if (slotg < 0) {
      float4 zz = {0.f, 0.f, 0.f, 0.f};
      *(float4*)(y + off) = zz;
      *(float4*)(y + off + 4) = zz;
    } else {
      int e = slotg / CAP, srow = slotg - e * CAP;
      int mt = srow >> 8, r = srow & 255;
      int kt = k0 >> 5, kk = k0 & 31;
      int p = r >> 1, g = ((r & 1) << 2) + (kk >> 3);
      size_t ou = (size_t)((e * 5 + mt) * 64 + kt) * 8192 + p * 64 + ((g ^ (p & 7)) << 3);
      *(uint4*)(xb2 + ou) = p4;
    }
    return;
  }
  const float* in; ushort* out; int eidx;
  if (z < 8) { in = wg; out = wgt; eidx = z; }
  else       { in = wu; out = wut; eidx = z - 8; }
  const int K = DH, N = DF;
  const int n0 = blockIdx.x * 64, k0 = blockIdx.y * 64;
  if (n0 >= N) return;
  __shared__ ushort T[64][72];
  const size_t eoff_in = (size_t)eidx * K * N;
  const int kr = tid >> 4;
  const int nc = (tid & 15) * 4;
#pragma unroll
  for (int it = 0; it < 4; ++it) {
    int k = k0 + kr + it * 16;
    int n = n0 + nc;
    float4 v = {0.f, 0.f, 0.f, 0.f};
    if (k < K && n + 4 <= N) v = *(const float4*)(in + eoff_in + (size_t)k * N + n);
    T[nc + 0][kr + it * 16] = bf16bits(v.x);
    T[nc + 1][kr + it * 16] = bf16bits(v.y);
    T[nc + 2][kr + it * 16] = bf16bits(v.z);
    T[nc + 3][kr + it * 16] = bf16bits(v.w);
  }
  __syncthreads();
  const int nr = tid >> 2;
  const int kc = tid & 3;
#pragma unroll
  for (int it = 0; it < 2; ++it) {
    int kloc = kc * 16 + it * 8;
    int n = n0 + nr, k = k0 + kloc;
    if (n < N && k + 8 <= K) {
      int nt = n >> 7, r = n & 127;
      int kt = k >> 5, kk = k & 31;
      int p = r >> 1, g = ((r & 1) << 2) + (kk >> 3);
      size_t ou = (size_t)((eidx * 11 + nt) * 64 + kt) * 4096 + p * 64 + ((g ^ (p & 7)) << 3);
      *(uint4*)(out + ou) = *(const uint4*)&T[nr][kloc];
    }
  }
}

// ---------------- prep2: wd [E][DF][DH] -> tiled-swizzled [e][nt16][kt43][8KB] ----------------
__global__ __launch_bounds__(256) void prep_wd(
    const float* __restrict__ wd, ushort* __restrict__ wdt) {
  const int eidx = blockIdx.z;
  const int K = DF, N = DH;
  const int n0 = blockIdx.x * 64, k0 = blockIdx.y * 64;
  __shared__ ushort T[64][72];
  const int tid = threadIdx.x;
  const size_t eoff_in = (size_t)eidx * K * N;
  const int kr = tid >> 4;
  const int nc = (tid & 15) * 4;
#pragma unroll
  for (int it = 0; it < 4; ++it) {
    int k = k0 + kr + it * 16;
    int n = n0 + nc;
    float4 v = {0.f, 0.f, 0.f, 0.f};
    if (k < K && n + 4 <= N) v = *(const float4*)(wd + eoff_in + (size_t)k * N + n);
    T[nc + 0][kr + it * 16] = bf16bits(v.x);
    T[nc + 1][kr + it * 16] = bf16bits(v.y);
    T[nc + 2][kr + it * 16] = bf16bits(v.z);
    T[nc + 3][kr + it * 16] = bf16bits(v.w);
  }
  __syncthreads();
  const int nr = tid >> 2;
  const int kc = tid & 3;
#pragma unroll
  for (int it = 0; it < 2; ++it) {
    int kloc = kc * 16 + it * 8;
    int n = n0 + nr, k = k0 + kloc;
    if (n < N && k + 8 <= K) {
      int nt = n >> 7, r = n & 127;
      int kt = k >> 5, kk = k & 31;
      int p = r >> 1, g = ((r & 1) << 2) + (kk >> 3);
      size_t ou = (size_t)((eidx * 16 + nt) * 43 + kt) * 4096 + p * 64 + ((g ^ (p & 7)) << 3);
      *(uint4*)(wdt + ou) = *(const uint4*)&T[nr][kloc];
    }
  }
}

// ======================================================================
// GEMM1 (256Mx128N, BK=32, QUAD-buffer, pipelined frags — r8 schedule):
//   h = silu(Xe*Wg) .* (Xe*Wu).  ALL staging lane-contiguous. [proven r13]
// ======================================================================
#define GU_READ(SET, RB) { \
  char* Ab_  = sm + (RB) * 16384; \
  char* Bgb_ = sm + 65536 + (RB) * 8192; \
  char* Bub_ = sm + 98304 + (RB) * 8192; \
  _Pragma("unroll") for (int i_ = 0; i_ < 4; ++i_) aR##SET[i_]  = *(const bf16x8*)(Ab_ + aoff[i_]); \
  _Pragma("unroll") for (int j_ = 0; j_ < 4; ++j_) bgR##SET[j_] = *(const bf16x8*)(Bgb_ + boff[j_]); \
  _Pragma("unroll") for (int j_ = 0; j_ < 4; ++j_) buR##SET[j_] = *(const bf16x8*)(Bub_ + boff[j_]); \
}
#define GU_MFMA(SET) { \
  _Pragma("unroll") for (int j_ = 0; j_ < 4; ++j_) \
    _Pragma("unroll") for (int i_ = 0; i_ < 4; ++i_) \
      accG[i_][j_] = __builtin_amdgcn_mfma_f32_16x16x32_bf16(aR##SET[i_], bgR##SET[j_], accG[i_][j_], 0, 0, 0); \
  _Pragma("unroll") for (int j_ = 0; j_ < 4; ++j_) \
    _Pragma("unroll") for (int i_ = 0; i_ < 4; ++i_) \
      accU[i_][j_] = __builtin_amdgcn_mfma_f32_16x16x32_bf16(aR##SET[i_], buR##SET[j_], accU[i_][j_], 0, 0, 0); \
}
#define GU_BODY(T, CUR, NXT) { \
  const int t_ = (T); \
  if (t_ + 3 < NT) { \
    const int w_ = (t_ + 3) & 3; \
    gload16(srcA[0] + (size_t)(t_ + 3) * 8192, (ushort*)(sm + w_ * 16384 + dstw)); \
    gload16(srcA[1] + (size_t)(t_ + 3) * 8192, (ushort*)(sm + w_ * 16384 + 8192 + dstw)); \
    gload16(srcBg + (size_t)(t_ + 3) * 4096, (ushort*)(sm + 65536 + w_ * 8192 + dstw)); \
    gload16(srcBu + (size_t)(t_ + 3) * 4096, (ushort*)(sm + 98304 + w_ * 8192 + dstw)); \
  } \
  if (t_ + 1 < NT) { GU_READ(NXT, (t_ + 1) & 3); LGKM(12); } else { LGKM(0); } \
  SCHED0(); SETPRIO(1); \
  GU_MFMA(CUR); \
  SETPRIO(0); SCHED0(); \
  if (t_ + 3 < NT) { WAITV(4); } else if (t_ + 2 < NT) { WAITV(0); } \
  BARRIER(); \
}

__global__ __launch_bounds__(512, 2) void gemm_gateup3(
    const ushort* __restrict__ xb2, const ushort* __restrict__ wgt,
    const ushort* __restrict__ wut, ushort* __restrict__ h)
{
  __shared__ __align__(16) char sm[131072];
  const int tid = threadIdx.x, lane = tid & 63, wid = tid >> 6;
  const int wr = wid >> 1, wc = wid & 1;
  const int l15 = lane & 15, l4 = lane >> 4;

  // XCD swizzle: 440 blocks = 8 XCDs x 55 (one expert: 5 mt x 11 nt)
  int wgid = (blockIdx.x & 7) * 55 + (blockIdx.x >> 3);
  const int e = wgid / 55;
  const int rem = wgid - e * 55;
  const int mt = rem / 11, nt = rem - (rem / 11) * 11;
  const int n0 = nt * 128;

  const ushort* srcA[2]; const ushort* srcBg; const ushort* srcBu;
  {
    const size_t abase = (size_t)((e * 5 + mt) * 64) * 8192;
    const int lo = (wid * 1024 + lane * 16) >> 1;
    srcA[0] = xb2 + abase + lo;
    srcA[1] = xb2 + abase + 4096 + lo;
    const size_t bbase = (size_t)((e * 11 + nt) * 64) * 4096;
    srcBg = wgt + bbase + lo;
    srcBu = wut + bbase + lo;
  }
  int aoff[4], boff[4];
#pragma unroll
  for (int i = 0; i < 4; ++i) aoff[i] = rp_off(wr * 64 + i * 16 + l15, l4);
#pragma unroll
  for (int j = 0; j < 4; ++j) boff[j] = rp_off(wc * 64 + j * 16 + l15, l4);
  const int dstw = wid * 1024;

  f32x4 accG[4][4], accU[4][4];
#pragma unroll
  for (int i = 0; i < 4; ++i)
#pragma unroll
    for (int j = 0; j < 4; ++j) {
      accG[i][j] = (f32x4){0.f, 0.f, 0.f, 0.f};
      accU[i][j] = (f32x4){0.f, 0.f, 0.f, 0.f};
    }

  const int NT = DH / 32;  // 64
#pragma unroll
  for (int t0 = 0; t0 < 3; ++t0) {
    gload16(srcA[0] + (size_t)t0 * 8192, (ushort*)(sm + t0 * 16384 + dstw));
    gload16(srcA[1] + (size_t)t0 * 8192, (ushort*)(sm + t0 * 16384 + 8192 + dstw));
    gload16(srcBg + (size_t)t0 * 4096, (ushort*)(sm + 65536 + t0 * 8192 + dstw));
    gload16(srcBu + (size_t)t0 * 4096, (ushort*)(sm + 98304 + t0 * 8192 + dstw));
  }
  WAITV(4);
  BARRIER();

  bf16x8 aR0[4], bgR0[4], buR0[4], aR1[4], bgR1[4], buR1[4];
  GU_READ(0, 0);

  for (int t = 0; t < NT; t += 2) {
    GU_BODY(t, 0, 1);
    GU_BODY(t + 1, 1, 0);
  }

  // epilogue: SwiGLU -> h in down's tiled-swizzled A layout
  const size_t hbase = (size_t)((e * 5 + mt) * 43) * 8192;
#pragma unroll
  for (int j = 0; j < 4; ++j) {
    int col = n0 + wc * 64 + j * 16 + l15;
    if (col < DF) {
      int kt = col >> 5, kk = col & 31;
      int gb = kk >> 3, ke = kk & 7;
      const size_t cb = hbase + (size_t)kt * 8192;
#pragma unroll
      for (int i = 0; i < 4; ++i)
#pragma unroll
        for (int r2 = 0; r2 < 4; ++r2) {
          int rowloc = wr * 64 + i * 16 + l4 * 4 + r2;
          int p = rowloc >> 1, g = ((rowloc & 1) << 2) + gb;
          float gv = accG[i][j][r2], uv = accU[i][j][r2];
          h[cb + p * 64 + ((g ^ (p & 7)) << 3) + ke] = bf16bits(gv / (1.f + __expf(-gv)) * uv);
        }
    }
  }
}

// ======================================================================
// GEMM2 (256Mx128N, BK=32, TRIPLE-buffer, NO frag read-ahead, 2 blocks/CU):
//   y[token] = (H*Wd)*score.  NT = 43.
// LDS 74KB: A[3][16KB]@0, B[3][8KB]@48K, tokc@72K, scc@73K -> 2 blocks/CU.
// Stage 2-ahead; end-of-iter WAITV(3) (just-issued stage outstanding) / 0.
// Mechanism test: inter-block overlap at CONSTANT per-block LDS traffic
// (r9 confounded this with tile halving).
// ======================================================================
__global__ __launch_bounds__(512, 4) void gemm_down4(
    const ushort* __restrict__ h, const ushort* __restrict__ wdt,
    const int* __restrict__ tok_slot, const float* __restrict__ scores,
    float* __restrict__ y)
{
  __shared__ __align__(16) char sm[75776];
  int* tokc = (int*)(sm + 73728);
  float* scc = (float*)(sm + 74752);
  const int tid = threadIdx.x, lane = tid & 63, wid = tid >> 6;
  const int wr = wid >> 1, wc = wid & 1;
  const int l15 = lane & 15, l4 = lane >> 4;

  // XCD swizzle: 640 blocks = 8 XCDs x 80 (one expert: 5 mt x 16 nt)
  int wgid = (blockIdx.x & 7) * 80 + (blockIdx.x >> 3);
  const int e = wgid / 80;
  const int rem = wgid - e * 80;
  const int mt = rem / 16, nt = rem & 15;
  const int n0 = nt * 128;

  if (tid < 256) {
    int tk = tok_slot[e * CAP + mt * 256 + tid];
    tokc[tid] = tk;
    scc[tid] = (tk >= 0) ? scores[tk] : 0.f;
  }
  __syncthreads();

  const ushort* srcA[2]; const ushort* srcB;
  {
    const size_t abase = (size_t)((e * 5 + mt) * 43) * 8192;
    const int lo = (wid * 1024 + lane * 16) >> 1;
    srcA[0] = h + abase + lo;
    srcA[1] = h + abase + 4096 + lo;
    srcB = wdt + (size_t)((e * 16 + nt) * 43) * 4096 + lo;
  }
  int aoff[4], boff[4];
#pragma unroll
  for (int i = 0; i < 4; ++i) aoff[i] = rp_off(wr * 64 + i * 16 + l15, l4);
#pragma unroll
  for (int j = 0; j < 4; ++j) boff[j] = rp_off(wc * 64 + j * 16 + l15, l4);
  const int dstw = wid * 1024;

  f32x4 acc[4][4];
#pragma unroll
  for (int i = 0; i < 4; ++i)
#pragma unroll
    for (int j = 0; j < 4; ++j) acc[i][j] = (f32x4){0.f, 0.f, 0.f, 0.f};

  const int NT = DF / 32;  // 43
  // prologue: stage tiles 0,1 (2-ahead)
#pragma unroll
  for (int t0 = 0; t0 < 2; ++t0) {
    gload16(srcA[0] + (size_t)t0 * 8192, (ushort*)(sm + t0 * 16384 + dstw));
    gload16(srcA[1] + (size_t)t0 * 8192, (ushort*)(sm + t0 * 16384 + 8192 + dstw));
    gload16(srcB + (size_t)t0 * 4096, (ushort*)(sm + 49152 + t0 * 8192 + dstw));
  }
  WAITV(3);       // tile0 landed; tile1 in flight
  BARRIER();

  int rb = 0, wb = 2;
  for (int t = 0; t < NT; ++t) {
    char* Ab = sm + rb * 16384;
    char* Bb = sm + 49152 + rb * 8192;
    if (t + 2 < NT) {
      gload16(srcA[0] + (size_t)(t + 2) * 8192, (ushort*)(sm + wb * 16384 + dstw));
      gload16(srcA[1] + (size_t)(t + 2) * 8192, (ushort*)(sm + wb * 16384 + 8192 + dstw));
      gload16(srcB + (size_t)(t + 2) * 4096, (ushort*)(sm + 49152 + wb * 8192 + dstw));
    }
    bf16x8 a[4], b[4];
#pragma unroll
    for (int i = 0; i < 4; ++i) a[i] = *(const bf16x8*)(Ab + aoff[i]);
#pragma unroll
    for (int j = 0; j < 4; ++j) b[j] = *(const bf16x8*)(Bb + boff[j]);
    LGKM(0); SCHED0();
    SETPRIO(1);
#pragma unroll
    for (int j = 0; j < 4; ++j)
#pragma unroll
      for (int i = 0; i < 4; ++i)
        acc[i][j] = __builtin_amdgcn_mfma_f32_16x16x32_bf16(a[i], b[j], acc[i][j], 0, 0, 0);
    SETPRIO(0); SCHED0();
    if (t + 2 < NT) { WAITV(3); } else { WAITV(0); }
    BARRIER();
    rb = (rb == 2) ? 0 : rb + 1;
    wb = (wb == 2) ? 0 : wb + 1;
  }
  // epilogue: scatter * score
  int tkr[4][4]; float sr[4][4];
#pragma unroll
  for (int i = 0; i < 4; ++i)
#pragma unroll
    for (int r = 0; r < 4; ++r) {
      int rl = wr * 64 + i * 16 + l4 * 4 + r;
      tkr[i][r] = tokc[rl];
      sr[i][r]  = scc[rl];
    }
#pragma unroll
  for (int j = 0; j < 4; ++j) {
    int col = n0 + wc * 64 + j * 16 + l15;
#pragma unroll
    for (int i = 0; i < 4; ++i)
#pragma unroll
      for (int r = 0; r < 4; ++r)
        if (tkr[i][r] >= 0)
          y[(size_t)tkr[i][r] * DH + col] = acc[i][j][r] * sr[i][r];
  }
}

extern "C" void kernel_launch(void* const* d_in, const int* in_sizes, int n_in,
                              void* d_out, int out_size, void* d_ws, size_t ws_size,
                              hipStream_t stream) {
  const float* x   = (const float*)d_in[0];
  const int*   idx = (const int*)d_in[1];
  const float* sc  = (const float*)d_in[2];
  const float* wg  = (const float*)d_in[3];
  const float* wu  = (const float*)d_in[4];
  const float* wd  = (const float*)d_in[5];
  float* y = (float*)d_out;

  // ws layout (~162.5 MB <= proven 197 MB): wdt reuses wgt region (prep_wd
  // runs after gateup).
  const size_t OFF_T2S = 40960;
  const size_t OFF_H   = OFF_T2S + 32768;                // 73728
  const size_t SZ_H    = (size_t)NE * 5 * 43 * 16384;    // 28,180,480
  const size_t OFF_XB  = OFF_H + SZ_H;
  const size_t SZ_XB   = (size_t)NE * 5 * 64 * 16384;    // 41,943,040
  const size_t OFF_WGT = OFF_XB + SZ_XB;
  const size_t SZ_WG   = (size_t)NE * 11 * 64 * 8192;    // 46,137,344
  const size_t OFF_WUT = OFF_WGT + SZ_WG;

  int* tok_slot = (int*)d_ws;
  int* tok2slot = (int*)((char*)d_ws + OFF_T2S);
  ushort* hbuf = (ushort*)((char*)d_ws + OFF_H);
  ushort* xb2  = (ushort*)((char*)d_ws + OFF_XB);
  ushort* wgt  = (ushort*)((char*)d_ws + OFF_WGT);
  ushort* wut  = (ushort*)((char*)d_ws + OFF_WUT);
  ushort* wdt  = wgt;   // dead after gateup; 45,088,768 <= 46,137,344

  hipLaunchKernelGGL(routing_kernel, dim3(1), dim3(256), 0, stream, idx, tok_slot, tok2slot);
  hipLaunchKernelGGL(prep1, dim3(32, 32, 24), dim3(256), 0, stream,
                     wg, wu, wgt, wut, x, tok2slot, xb2, y);
  hipLaunchKernelGGL(gemm_gateup3, dim3(440), dim3(512), 0, stream,
                     xb2, wgt, wut, hbuf);
  hipLaunchKernelGGL(prep_wd, dim3(32, 22, 8), dim3(256), 0, stream, wd, wdt);
  hipLaunchKernelGGL(gemm_down4, dim3(640), dim3(512), 0, stream,
                     hbuf, wdt, tok_slot, sc, y);
}

// Round 15
// 315.034 us; speedup vs baseline: 1.0094x; 1.0094x over previous
//
#include <hip/hip_runtime.h>
#include <hip/hip_bf16.h>
#include <cstdint>
#include <cstddef>

#define NTOK 8192
#define DH   2048
#define DF   1376
#define NE   8
#define CAP  1280

typedef __bf16 bf16x8 __attribute__((ext_vector_type(8)));
typedef float  f32x4  __attribute__((ext_vector_type(4)));

#define BARRIER() asm volatile("s_barrier" ::: "memory")
#define WAITV(n)  asm volatile("s_waitcnt vmcnt(" #n ")" ::: "memory")
#define LGKM(n)   asm volatile("s_waitcnt lgkmcnt(" #n ")" ::: "memory")
#define SCHED0()  __builtin_amdgcn_sched_barrier(0)
#define SETPRIO(n) __builtin_amdgcn_s_setprio(n)

__device__ __forceinline__ uint32_t pk2(float a, float b) {
  float2 f; f.x = a; f.y = b;
  union { __hip_bfloat162 h; uint32_t u; } cv;
  cv.h = __float22bfloat162_rn(f);
  return cv.u;
}
__device__ __forceinline__ ushort bf16bits(float a) {
  return (ushort)(pk2(a, 0.f) & 0xFFFFu);
}
__device__ __forceinline__ void gload16(const ushort* g, ushort* l) {
  __builtin_amdgcn_global_load_lds(
      (const __attribute__((address_space(1))) uint32_t*)(const void*)g,
      (__attribute__((address_space(3))) uint32_t*)(void*)l,
      16, 0, 0);
}

// rowpair-128B swizzle (proven 0-conflict), baked into the global operand
// buffers by prep, so all global_load_lds are lane-contiguous.
// element (row,k) -> ushort offset within tile:
//   p=row>>1, g=(row&1)*4 + k/8, off_u = p*64 + ((g^(p&7))<<3) + (k%8)
__device__ __forceinline__ int rp_off(int row, int l4) {
  return ((row >> 1) << 7) + (((((row & 1) << 2) + l4) ^ ((row >> 1) & 7)) << 4);
}

// ---------------- routing: slot<-token and token->slot maps ----------------
__global__ void routing_kernel(const int* __restrict__ idx, int* __restrict__ tok_slot,
                               int* __restrict__ tok2slot) {
  __shared__ int cnt[256][NE];
  const int t = threadIdx.x;
  for (int s = t; s < NE * CAP; s += 256) tok_slot[s] = -1;
  unsigned long long cA = 0ull, cB = 0ull;
  const int per = NTOK / 256, base = t * per;
  for (int i = 0; i < per; ++i) {
    int e = idx[base + i];
    unsigned long long inc = 1ull << ((e & 3) * 16);
    if (e < 4) cA += inc; else cB += inc;
  }
#pragma unroll
  for (int e = 0; e < 4; ++e) cnt[t][e]     = (int)((cA >> (e * 16)) & 0xFFFF);
#pragma unroll
  for (int e = 0; e < 4; ++e) cnt[t][4 + e] = (int)((cB >> (e * 16)) & 0xFFFF);
  __syncthreads();
  if (t < NE) {
    int run = 0;
    for (int i = 0; i < 256; ++i) { int c = cnt[i][t]; cnt[i][t] = run; run += c; }
  }
  __syncthreads();
  cA = 0ull; cB = 0ull;
#pragma unroll
  for (int e = 0; e < 4; ++e) cA |= (unsigned long long)(cnt[t][e] & 0xFFFF) << (e * 16);
#pragma unroll
  for (int e = 0; e < 4; ++e) cB |= (unsigned long long)(cnt[t][4 + e] & 0xFFFF) << (e * 16);
  for (int i = 0; i < per; ++i) {
    int token = base + i;
    int e = idx[token];
    int sh = (e & 3) * 16;
    int r = (int)(((e < 4 ? cA : cB) >> sh) & 0xFFFF);
    unsigned long long inc = 1ull << sh;
    if (e < 4) cA += inc; else cB += inc;
    bool keep = (r < CAP);
    tok2slot[token] = keep ? (e * CAP + r) : -1;
    if (keep) tok_slot[e * CAP + r] = token;
  }
}

// ---------------- prep1: z<8 wg, z<16 wu -> tiled-swizzled; z>=16 x -> gathered tiled xb2 + y-zero ----------------
__global__ __launch_bounds__(256) void prep1(
    const float* __restrict__ wg, const float* __restrict__ wu,
    ushort* __restrict__ wgt, ushort* __restrict__ wut,
    const float* __restrict__ x, const int* __restrict__ tok2slot,
    ushort* __restrict__ xb2, float* __restrict__ y) {
  const int z = blockIdx.z;
  const int tid = threadIdx.x;
  if (z >= 16) {
    // one token row per block, one 8-elem granule per thread
    const int row = (z - 16) * 1024 + blockIdx.y * 32 + blockIdx.x;
    const int k0 = tid * 8;
    const size_t off = (size_t)row * DH + k0;
    float4 a = *(const float4*)(x + off);
    float4 b = *(const float4*)(x + off + 4);
    uint4 p4 = { pk2(a.x, a.y), pk2(a.z, a.w), pk2(b.x, b.y), pk2(b.z, b.w) };
    int slotg = tok2slot[row];
    if (slotg < 0) {
      float4 zz = {0.f, 0.f, 0.f, 0.f};
      *(float4*)(y + off) = zz;
      *(float4*)(y + off + 4) = zz;
    } else {
      int e = slotg / CAP, srow = slotg - e * CAP;
      int mt = srow >> 8, r = srow & 255;
      int kt = k0 >> 5, kk = k0 & 31;
      int p = r >> 1, g = ((r & 1) << 2) + (kk >> 3);
      size_t ou = (size_t)((e * 5 + mt) * 64 + kt) * 8192 + p * 64 + ((g ^ (p & 7)) << 3);
      *(uint4*)(xb2 + ou) = p4;
    }
    return;
  }
  const float* in; ushort* out; int eidx;
  if (z < 8) { in = wg; out = wgt; eidx = z; }
  else       { in = wu; out = wut; eidx = z - 8; }
  const int K = DH, N = DF;
  const int n0 = blockIdx.x * 64, k0 = blockIdx.y * 64;
  if (n0 >= N) return;
  __shared__ ushort T[64][72];
  const size_t eoff_in = (size_t)eidx * K * N;
  const int kr = tid >> 4;
  const int nc = (tid & 15) * 4;
#pragma unroll
  for (int it = 0; it < 4; ++it) {
    int k = k0 + kr + it * 16;
    int n = n0 + nc;
    float4 v = {0.f, 0.f, 0.f, 0.f};
    if (k < K && n + 4 <= N) v = *(const float4*)(in + eoff_in + (size_t)k * N + n);
    T[nc + 0][kr + it * 16] = bf16bits(v.x);
    T[nc + 1][kr + it * 16] = bf16bits(v.y);
    T[nc + 2][kr + it * 16] = bf16bits(v.z);
    T[nc + 3][kr + it * 16] = bf16bits(v.w);
  }
  __syncthreads();
  const int nr = tid >> 2;
  const int kc = tid & 3;
#pragma unroll
  for (int it = 0; it < 2; ++it) {
    int kloc = kc * 16 + it * 8;
    int n = n0 + nr, k = k0 + kloc;
    if (n < N && k + 8 <= K) {
      int nt = n >> 7, r = n & 127;
      int kt = k >> 5, kk = k & 31;
      int p = r >> 1, g = ((r & 1) << 2) + (kk >> 3);
      size_t ou = (size_t)((eidx * 11 + nt) * 64 + kt) * 4096 + p * 64 + ((g ^ (p & 7)) << 3);
      *(uint4*)(out + ou) = *(const uint4*)&T[nr][kloc];
    }
  }
}

// ---------------- prep2: wd [E][DF][DH] -> tiled-swizzled [e][nt16][kt43][8KB] ----------------
__global__ __launch_bounds__(256) void prep_wd(
    const float* __restrict__ wd, ushort* __restrict__ wdt) {
  const int eidx = blockIdx.z;
  const int K = DF, N = DH;
  const int n0 = blockIdx.x * 64, k0 = blockIdx.y * 64;
  __shared__ ushort T[64][72];
  const int tid = threadIdx.x;
  const size_t eoff_in = (size_t)eidx * K * N;
  const int kr = tid >> 4;
  const int nc = (tid & 15) * 4;
#pragma unroll
  for (int it = 0; it < 4; ++it) {
    int k = k0 + kr + it * 16;
    int n = n0 + nc;
    float4 v = {0.f, 0.f, 0.f, 0.f};
    if (k < K && n + 4 <= N) v = *(const float4*)(wd + eoff_in + (size_t)k * N + n);
    T[nc + 0][kr + it * 16] = bf16bits(v.x);
    T[nc + 1][kr + it * 16] = bf16bits(v.y);
    T[nc + 2][kr + it * 16] = bf16bits(v.z);
    T[nc + 3][kr + it * 16] = bf16bits(v.w);
  }
  __syncthreads();
  const int nr = tid >> 2;
  const int kc = tid & 3;
#pragma unroll
  for (int it = 0; it < 2; ++it) {
    int kloc = kc * 16 + it * 8;
    int n = n0 + nr, k = k0 + kloc;
    if (n < N && k + 8 <= K) {
      int nt = n >> 7, r = n & 127;
      int kt = k >> 5, kk = k & 31;
      int p = r >> 1, g = ((r & 1) << 2) + (kk >> 3);
      size_t ou = (size_t)((eidx * 16 + nt) * 43 + kt) * 4096 + p * 64 + ((g ^ (p & 7)) << 3);
      *(uint4*)(wdt + ou) = *(const uint4*)&T[nr][kloc];
    }
  }
}

// ======================================================================
// GEMM1 (256Mx128N, BK=32, QUAD-buffer, pipelined frags — r8 schedule):
//   h = silu(Xe*Wg) .* (Xe*Wu).  ALL staging lane-contiguous. [proven r13]
// ======================================================================
#define GU_READ(SET, RB) { \
  char* Ab_  = sm + (RB) * 16384; \
  char* Bgb_ = sm + 65536 + (RB) * 8192; \
  char* Bub_ = sm + 98304 + (RB) * 8192; \
  _Pragma("unroll") for (int i_ = 0; i_ < 4; ++i_) aR##SET[i_]  = *(const bf16x8*)(Ab_ + aoff[i_]); \
  _Pragma("unroll") for (int j_ = 0; j_ < 4; ++j_) bgR##SET[j_] = *(const bf16x8*)(Bgb_ + boff[j_]); \
  _Pragma("unroll") for (int j_ = 0; j_ < 4; ++j_) buR##SET[j_] = *(const bf16x8*)(Bub_ + boff[j_]); \
}
#define GU_MFMA(SET) { \
  _Pragma("unroll") for (int j_ = 0; j_ < 4; ++j_) \
    _Pragma("unroll") for (int i_ = 0; i_ < 4; ++i_) \
      accG[i_][j_] = __builtin_amdgcn_mfma_f32_16x16x32_bf16(aR##SET[i_], bgR##SET[j_], accG[i_][j_], 0, 0, 0); \
  _Pragma("unroll") for (int j_ = 0; j_ < 4; ++j_) \
    _Pragma("unroll") for (int i_ = 0; i_ < 4; ++i_) \
      accU[i_][j_] = __builtin_amdgcn_mfma_f32_16x16x32_bf16(aR##SET[i_], buR##SET[j_], accU[i_][j_], 0, 0, 0); \
}
#define GU_BODY(T, CUR, NXT) { \
  const int t_ = (T); \
  if (t_ + 3 < NT) { \
    const int w_ = (t_ + 3) & 3; \
    gload16(srcA[0] + (size_t)(t_ + 3) * 8192, (ushort*)(sm + w_ * 16384 + dstw)); \
    gload16(srcA[1] + (size_t)(t_ + 3) * 8192, (ushort*)(sm + w_ * 16384 + 8192 + dstw)); \
    gload16(srcBg + (size_t)(t_ + 3) * 4096, (ushort*)(sm + 65536 + w_ * 8192 + dstw)); \
    gload16(srcBu + (size_t)(t_ + 3) * 4096, (ushort*)(sm + 98304 + w_ * 8192 + dstw)); \
  } \
  if (t_ + 1 < NT) { GU_READ(NXT, (t_ + 1) & 3); LGKM(12); } else { LGKM(0); } \
  SCHED0(); SETPRIO(1); \
  GU_MFMA(CUR); \
  SETPRIO(0); SCHED0(); \
  if (t_ + 3 < NT) { WAITV(4); } else if (t_ + 2 < NT) { WAITV(0); } \
  BARRIER(); \
}

__global__ __launch_bounds__(512, 2) void gemm_gateup3(
    const ushort* __restrict__ xb2, const ushort* __restrict__ wgt,
    const ushort* __restrict__ wut, ushort* __restrict__ h)
{
  __shared__ __align__(16) char sm[131072];
  const int tid = threadIdx.x, lane = tid & 63, wid = tid >> 6;
  const int wr = wid >> 1, wc = wid & 1;
  const int l15 = lane & 15, l4 = lane >> 4;

  // XCD swizzle: 440 blocks = 8 XCDs x 55 (one expert: 5 mt x 11 nt)
  int wgid = (blockIdx.x & 7) * 55 + (blockIdx.x >> 3);
  const int e = wgid / 55;
  const int rem = wgid - e * 55;
  const int mt = rem / 11, nt = rem - (rem / 11) * 11;
  const int n0 = nt * 128;

  const ushort* srcA[2]; const ushort* srcBg; const ushort* srcBu;
  {
    const size_t abase = (size_t)((e * 5 + mt) * 64) * 8192;
    const int lo = (wid * 1024 + lane * 16) >> 1;
    srcA[0] = xb2 + abase + lo;
    srcA[1] = xb2 + abase + 4096 + lo;
    const size_t bbase = (size_t)((e * 11 + nt) * 64) * 4096;
    srcBg = wgt + bbase + lo;
    srcBu = wut + bbase + lo;
  }
  int aoff[4], boff[4];
#pragma unroll
  for (int i = 0; i < 4; ++i) aoff[i] = rp_off(wr * 64 + i * 16 + l15, l4);
#pragma unroll
  for (int j = 0; j < 4; ++j) boff[j] = rp_off(wc * 64 + j * 16 + l15, l4);
  const int dstw = wid * 1024;

  f32x4 accG[4][4], accU[4][4];
#pragma unroll
  for (int i = 0; i < 4; ++i)
#pragma unroll
    for (int j = 0; j < 4; ++j) {
      accG[i][j] = (f32x4){0.f, 0.f, 0.f, 0.f};
      accU[i][j] = (f32x4){0.f, 0.f, 0.f, 0.f};
    }

  const int NT = DH / 32;  // 64
#pragma unroll
  for (int t0 = 0; t0 < 3; ++t0) {
    gload16(srcA[0] + (size_t)t0 * 8192, (ushort*)(sm + t0 * 16384 + dstw));
    gload16(srcA[1] + (size_t)t0 * 8192, (ushort*)(sm + t0 * 16384 + 8192 + dstw));
    gload16(srcBg + (size_t)t0 * 4096, (ushort*)(sm + 65536 + t0 * 8192 + dstw));
    gload16(srcBu + (size_t)t0 * 4096, (ushort*)(sm + 98304 + t0 * 8192 + dstw));
  }
  WAITV(4);       // tiles 0,1 landed; {2} in flight
  BARRIER();

  bf16x8 aR0[4], bgR0[4], buR0[4], aR1[4], bgR1[4], buR1[4];
  GU_READ(0, 0);

  for (int t = 0; t < NT; t += 2) {
    GU_BODY(t, 0, 1);
    GU_BODY(t + 1, 1, 0);
  }

  // epilogue: SwiGLU -> h in down's tiled-swizzled A layout
  const size_t hbase = (size_t)((e * 5 + mt) * 43) * 8192;
#pragma unroll
  for (int j = 0; j < 4; ++j) {
    int col = n0 + wc * 64 + j * 16 + l15;
    if (col < DF) {
      int kt = col >> 5, kk = col & 31;
      int gb = kk >> 3, ke = kk & 7;
      const size_t cb = hbase + (size_t)kt * 8192;
#pragma unroll
      for (int i = 0; i < 4; ++i)
#pragma unroll
        for (int r2 = 0; r2 < 4; ++r2) {
          int rowloc = wr * 64 + i * 16 + l4 * 4 + r2;
          int p = rowloc >> 1, g = ((rowloc & 1) << 2) + gb;
          float gv = accG[i][j][r2], uv = accU[i][j][r2];
          h[cb + p * 64 + ((g ^ (p & 7)) << 3) + ke] = bf16bits(gv / (1.f + __expf(-gv)) * uv);
        }
    }
  }
}

// ======================================================================
// GEMM2 (256Mx128N, BK=32, QUAD-buffer, pipelined frags — r8 schedule):
//   y[token] = (H*Wd)*score.  NT = 43. All staging lane-contiguous.
// ======================================================================
#define DN_READ(SET, RB) { \
  char* Ab_ = sm + (RB) * 16384; \
  char* Bb_ = sm + 65536 + (RB) * 8192; \
  _Pragma("unroll") for (int i_ = 0; i_ < 4; ++i_) aR##SET[i_] = *(const bf16x8*)(Ab_ + aoff[i_]); \
  _Pragma("unroll") for (int j_ = 0; j_ < 4; ++j_) bR##SET[j_] = *(const bf16x8*)(Bb_ + boff[j_]); \
}
#define DN_MFMA(SET) { \
  _Pragma("unroll") for (int j_ = 0; j_ < 4; ++j_) \
    _Pragma("unroll") for (int i_ = 0; i_ < 4; ++i_) \
      acc[i_][j_] = __builtin_amdgcn_mfma_f32_16x16x32_bf16(aR##SET[i_], bR##SET[j_], acc[i_][j_], 0, 0, 0); \
}
#define DN_BODY(T, CUR, NXT) { \
  const int t_ = (T); \
  if (t_ + 3 < NT) { \
    const int w_ = (t_ + 3) & 3; \
    gload16(srcA[0] + (size_t)(t_ + 3) * 8192, (ushort*)(sm + w_ * 16384 + dstw)); \
    gload16(srcA[1] + (size_t)(t_ + 3) * 8192, (ushort*)(sm + w_ * 16384 + 8192 + dstw)); \
    gload16(srcB + (size_t)(t_ + 3) * 4096, (ushort*)(sm + 65536 + w_ * 8192 + dstw)); \
  } \
  if (t_ + 1 < NT) { DN_READ(NXT, (t_ + 1) & 3); LGKM(8); } else { LGKM(0); } \
  SCHED0(); SETPRIO(1); \
  DN_MFMA(CUR); \
  SETPRIO(0); SCHED0(); \
  if (t_ + 3 < NT) { WAITV(3); } else if (t_ + 2 < NT) { WAITV(0); } \
  BARRIER(); \
}

__global__ __launch_bounds__(512, 2) void gemm_down3(
    const ushort* __restrict__ h, const ushort* __restrict__ wdt,
    const int* __restrict__ tok_slot, const float* __restrict__ scores,
    float* __restrict__ y)
{
  __shared__ __align__(16) char sm[100352];
  int* tokc = (int*)(sm + 98304);
  float* scc = (float*)(sm + 99328);
  const int tid = threadIdx.x, lane = tid & 63, wid = tid >> 6;
  const int wr = wid >> 1, wc = wid & 1;
  const int l15 = lane & 15, l4 = lane >> 4;

  // XCD swizzle: 640 blocks = 8 XCDs x 80 (one expert: 5 mt x 16 nt)
  int wgid = (blockIdx.x & 7) * 80 + (blockIdx.x >> 3);
  const int e = wgid / 80;
  const int rem = wgid - e * 80;
  const int mt = rem / 16, nt = rem & 15;
  const int n0 = nt * 128;

  if (tid < 256) {
    int tk = tok_slot[e * CAP + mt * 256 + tid];
    tokc[tid] = tk;
    scc[tid] = (tk >= 0) ? scores[tk] : 0.f;
  }
  __syncthreads();

  const ushort* srcA[2]; const ushort* srcB;
  {
    const size_t abase = (size_t)((e * 5 + mt) * 43) * 8192;
    const int lo = (wid * 1024 + lane * 16) >> 1;
    srcA[0] = h + abase + lo;
    srcA[1] = h + abase + 4096 + lo;
    srcB = wdt + (size_t)((e * 16 + nt) * 43) * 4096 + lo;
  }
  int aoff[4], boff[4];
#pragma unroll
  for (int i = 0; i < 4; ++i) aoff[i] = rp_off(wr * 64 + i * 16 + l15, l4);
#pragma unroll
  for (int j = 0; j < 4; ++j) boff[j] = rp_off(wc * 64 + j * 16 + l15, l4);
  const int dstw = wid * 1024;

  f32x4 acc[4][4];
#pragma unroll
  for (int i = 0; i < 4; ++i)
#pragma unroll
    for (int j = 0; j < 4; ++j) acc[i][j] = (f32x4){0.f, 0.f, 0.f, 0.f};

  const int NT = DF / 32;  // 43
#pragma unroll
  for (int t0 = 0; t0 < 3; ++t0) {
    gload16(srcA[0] + (size_t)t0 * 8192, (ushort*)(sm + t0 * 16384 + dstw));
    gload16(srcA[1] + (size_t)t0 * 8192, (ushort*)(sm + t0 * 16384 + 8192 + dstw));
    gload16(srcB + (size_t)t0 * 4096, (ushort*)(sm + 65536 + t0 * 8192 + dstw));
  }
  WAITV(3);       // tiles 0,1 landed; {2} in flight
  BARRIER();

  bf16x8 aR0[4], bR0[4], aR1[4], bR1[4];
  DN_READ(0, 0);

  for (int t = 0; t < NT - 1; t += 2) {   // 21 pairs: t = 0..41
    DN_BODY(t, 0, 1);
    DN_BODY(t + 1, 1, 0);
  }
  DN_BODY(NT - 1, 0, 1);                  // tail t = 42 (uses set 0)

  // epilogue: scatter * score
  int tkr[4][4]; float sr[4][4];
#pragma unroll
  for (int i = 0; i < 4; ++i)
#pragma unroll
    for (int r = 0; r < 4; ++r) {
      int rl = wr * 64 + i * 16 + l4 * 4 + r;
      tkr[i][r] = tokc[rl];
      sr[i][r]  = scc[rl];
    }
#pragma unroll
  for (int j = 0; j < 4; ++j) {
    int col = n0 + wc * 64 + j * 16 + l15;
#pragma unroll
    for (int i = 0; i < 4; ++i)
#pragma unroll
      for (int r = 0; r < 4; ++r)
        if (tkr[i][r] >= 0)
          y[(size_t)tkr[i][r] * DH + col] = acc[i][j][r] * sr[i][r];
  }
}

extern "C" void kernel_launch(void* const* d_in, const int* in_sizes, int n_in,
                              void* d_out, int out_size, void* d_ws, size_t ws_size,
                              hipStream_t stream) {
  const float* x   = (const float*)d_in[0];
  const int*   idx = (const int*)d_in[1];
  const float* sc  = (const float*)d_in[2];
  const float* wg  = (const float*)d_in[3];
  const float* wu  = (const float*)d_in[4];
  const float* wd  = (const float*)d_in[5];
  float* y = (float*)d_out;

  // ws layout (~162.5 MB <= proven 197 MB): wdt reuses wgt region (prep_wd
  // runs after gateup).
  const size_t OFF_T2S = 40960;                          // tok_slot [0,40960)
  const size_t OFF_H   = OFF_T2S + 32768;                // 73728
  const size_t SZ_H    = (size_t)NE * 5 * 43 * 16384;    // 28,180,480
  const size_t OFF_XB  = OFF_H + SZ_H;                   // 28,254,208
  const size_t SZ_XB   = (size_t)NE * 5 * 64 * 16384;    // 41,943,040
  const size_t OFF_WGT = OFF_XB + SZ_XB;                 // 70,197,248
  const size_t SZ_WG   = (size_t)NE * 11 * 64 * 8192;    // 46,137,344
  const size_t OFF_WUT = OFF_WGT + SZ_WG;                // 116,334,592

  int* tok_slot = (int*)d_ws;
  int* tok2slot = (int*)((char*)d_ws + OFF_T2S);
  ushort* hbuf = (ushort*)((char*)d_ws + OFF_H);
  ushort* xb2  = (ushort*)((char*)d_ws + OFF_XB);
  ushort* wgt  = (ushort*)((char*)d_ws + OFF_WGT);
  ushort* wut  = (ushort*)((char*)d_ws + OFF_WUT);
  ushort* wdt  = wgt;   // dead after gateup; 45,088,768 <= 46,137,344

  hipLaunchKernelGGL(routing_kernel, dim3(1), dim3(256), 0, stream, idx, tok_slot, tok2slot);
  hipLaunchKernelGGL(prep1, dim3(32, 32, 24), dim3(256), 0, stream,
                     wg, wu, wgt, wut, x, tok2slot, xb2, y);
  hipLaunchKernelGGL(gemm_gateup3, dim3(440), dim3(512), 0, stream,
                     xb2, wgt, wut, hbuf);
  hipLaunchKernelGGL(prep_wd, dim3(32, 22, 8), dim3(256), 0, stream, wd, wdt);
  hipLaunchKernelGGL(gemm_down3, dim3(640), dim3(512), 0, stream,
                     hbuf, wdt, tok_slot, sc, y);
}